// Round 3
// baseline (91.338 us; speedup 1.0000x reference)
//
#include <hip/hip_runtime.h>

#define DEVINL __device__ __forceinline__

typedef float f2 __attribute__((ext_vector_type(2)));

DEVINL float rcp_fast(float x) { return __builtin_amdgcn_rcpf(x); }

#if __has_builtin(__builtin_amdgcn_exp2f)
DEVINL float exp2_fast(float x) { return __builtin_amdgcn_exp2f(x); }
#else
DEVINL float exp2_fast(float x) { return exp2f(x); }
#endif

// Broadcast lane L (0..3) of each 4-lane quad to all 4 lanes (DPP quad_perm).
template <int L>
DEVINL float qbcast(float v) {
    return __int_as_float(__builtin_amdgcn_update_dpp(
        0, __float_as_int(v), L * 0x55, 0xF, 0xF, true));
}

DEVINL f2 splat2(float s) { f2 r; r.x = s; r.y = s; return r; }

constexpr float L2E = 1.4426950408889634f;   // log2(e)
constexpr float K2  = 2.8853900817779268f;   // 2*log2(e)

// Grid barrier across 16 blocks: ticket counter in ws, zeroed per call by a
// captured hipMemsetAsync node. All 16 blocks are trivially co-resident
// (16 blocks x 256 thr on a 256-CU chip), so the spin cannot deadlock.
DEVINL void grid_bar(int* ctr, int target) {
    __threadfence();                       // release my writes to device scope
    __syncthreads();                       // whole block fenced
    if (threadIdx.x == 0) {
        __hip_atomic_fetch_add(ctr, 1, __ATOMIC_ACQ_REL, __HIP_MEMORY_SCOPE_AGENT);
        while (__hip_atomic_load(ctr, __ATOMIC_ACQUIRE, __HIP_MEMORY_SCOPE_AGENT) < target)
            __builtin_amdgcn_s_sleep(1);
    }
    __syncthreads();
    __threadfence();                       // acquire: see other blocks' writes
}

// ---------------------------------------------------------------------------
// One fused kernel, 16 blocks x 256 threads:
//  Phase E  (wave0/block): encoder LSTM, quad-per-batch, 16 batches/block
//  Phase F1 (all 64 waves): fc1 512x1000, 8 contiguous rows/wave
//  Phase F2 (all 64 waves): fc2 250x512, 4 contiguous rows/wave
//  Phase D  (wave0 of blocks 0-3): decoder LSTM, scalar-per-lane (H=1)
// ---------------------------------------------------------------------------
__global__ __launch_bounds__(256) void fused_kernel(
    const float* __restrict__ x,        // (250,250) (t,b)
    const float* __restrict__ h0_dec,   // (250,)
    const float* __restrict__ ewih,     // (16,1)
    const float* __restrict__ ewhh,     // (16,4)
    const float* __restrict__ ebias,    // (16,)
    const float* __restrict__ fc1_w,    // (512,1000)
    const float* __restrict__ fc1_b,    // (512,)
    const float* __restrict__ fc2_w,    // (250,512)
    const float* __restrict__ fc2_b,    // (250,)
    const float* __restrict__ dwih,     // (4,4)
    const float* __restrict__ dwhh,     // (4,1)
    const float* __restrict__ dbias,    // (4,)
    float* __restrict__ out,            // (250,250) (t,b)
    float* __restrict__ yws,            // (250,250,4)
    float* __restrict__ cfin,           // (250,4) -> flat (1000,)
    float* __restrict__ out1,           // (512,)
    float* __restrict__ c0dec,          // (250,)
    float* __restrict__ dump,           // scratch, never read
    int* __restrict__ ctr)              // barrier counter (zeroed per call)
{
    const int tid = threadIdx.x;
    const int blk = blockIdx.x;

    // ---------------- Phase E: encoder ----------------
    if (tid < 64) {
        const int b0 = blk * 16;
        const int bl = tid >> 2;
        const int u  = tid & 3;
        const int b  = b0 + bl;
        const bool bv = b < 250;
        const int bs = bv ? b : 0;

        // Pre-scale: sigmoid rows (i,f,o) by -log2e, tanh row (g) by +2log2e.
        const float sI = -L2E, sF = -L2E, sG = 2.0f * L2E, sO = -L2E;
        f2 wihA, wihB, bbA, bbB, whhA[4], whhB[4];
        wihA.x = ewih[u]      * sI;  wihA.y = ewih[4 + u]  * sF;
        wihB.x = ewih[8 + u]  * sG;  wihB.y = ewih[12 + u] * sO;
        bbA.x  = ebias[u]     * sI;  bbA.y  = ebias[4 + u] * sF;
        bbB.x  = ebias[8 + u] * sG;  bbB.y  = ebias[12 + u]* sO;
#pragma unroll
        for (int j = 0; j < 4; ++j) {
            whhA[j].x = ewhh[u * 4 + j]        * sI;
            whhA[j].y = ewhh[(4 + u) * 4 + j]  * sF;
            whhB[j].x = ewhh[(8 + u) * 4 + j]  * sG;
            whhB[j].y = ewhh[(12 + u) * 4 + j] * sO;
        }

        float h = 0.0f, c = 0.0f;
        float xA = x[(0 + u) * 250 + bs];
        float xB = x[(4 + u) * 250 + bs];

        float* yp = bv ? (yws + b * 4 + u) : (dump + blk * 64 + tid);
        const int yinc = bv ? 1000 : 0;

#define ENC_STEP(XR, Q) do {                                                  \
    const float xt = qbcast<Q>(XR);                                           \
    const float h0 = qbcast<0>(h), h1 = qbcast<1>(h);                         \
    const float h2 = qbcast<2>(h), h3 = qbcast<3>(h);                         \
    f2 aA = splat2(xt) * wihA + bbA;                                          \
    f2 aB = splat2(xt) * wihB + bbB;                                          \
    f2 tA = splat2(h1) * whhA[1] + (splat2(h0) * whhA[0] + aA);               \
    f2 uA = splat2(h3) * whhA[3] + (splat2(h2) * whhA[2]);                    \
    f2 tB = splat2(h1) * whhB[1] + (splat2(h0) * whhB[0] + aB);               \
    f2 uB = splat2(h3) * whhB[3] + (splat2(h2) * whhB[2]);                    \
    const f2 accA = tA + uA;                                                  \
    const f2 accB = tB + uB;                                                  \
    const float ri = rcp_fast(1.0f + exp2_fast(accA.x));                      \
    const float rf = rcp_fast(1.0f + exp2_fast(accA.y));                      \
    const float rg = rcp_fast(1.0f + exp2_fast(accB.x));                      \
    const float ro = rcp_fast(1.0f + exp2_fast(accB.y));                      \
    const float tg = fmaf(-2.0f, rg, 1.0f);                                   \
    c = fmaf(ri, tg, rf * c);                                                 \
    const float n2so = -2.0f * ro;                                            \
    const float r2 = rcp_fast(1.0f + exp2_fast(c * K2));                      \
    h = fmaf(n2so, r2, ro);                                                   \
    *yp = h; yp += yinc;                                                      \
} while (0)

        for (int tb = 0; tb < 62; ++tb) {
            const int tn = (tb + 2) * 4 + u;
            const float xC = x[min(tn, 249) * 250 + bs];
            ENC_STEP(xA, 0); ENC_STEP(xA, 1); ENC_STEP(xA, 2); ENC_STEP(xA, 3);
            xA = xB; xB = xC;
        }
        ENC_STEP(xA, 0); ENC_STEP(xA, 1);   // steps 248, 249
#undef ENC_STEP

        if (bv) cfin[b * 4 + u] = c;
    }

    grid_bar(ctr, 16);

    // ---------------- Phase F1: fc1 (512 rows x 1000) ----------------
    {
        const int gw = blk * 4 + (tid >> 6);   // 0..63
        const int lane = tid & 63;
        const int r0 = gw * 8;
        float acc[8] = {0, 0, 0, 0, 0, 0, 0, 0};
        for (int n = lane; n < 1000; n += 64) {
            const float s = cfin[n];
#pragma unroll
            for (int j = 0; j < 8; ++j)
                acc[j] = fmaf(s, fc1_w[(r0 + j) * 1000 + n], acc[j]);
        }
#pragma unroll
        for (int j = 0; j < 8; ++j) {
            float a = acc[j];
#pragma unroll
            for (int m = 32; m; m >>= 1) a += __shfl_xor(a, m, 64);
            if (lane == 0) out1[r0 + j] = fmaxf(a + fc1_b[r0 + j], 0.0f);
        }
    }

    grid_bar(ctr, 32);

    // ---------------- Phase F2: fc2 (250 rows x 512) ----------------
    {
        const int gw = blk * 4 + (tid >> 6);
        const int lane = tid & 63;
        const int r0 = gw * 4;
        float acc[4] = {0, 0, 0, 0};
        for (int n = lane; n < 512; n += 64) {
            const float v = out1[n];
#pragma unroll
            for (int j = 0; j < 4; ++j) {
                const int rr = min(r0 + j, 249);   // clamp to stay in-bounds
                acc[j] = fmaf(v, fc2_w[rr * 512 + n], acc[j]);
            }
        }
#pragma unroll
        for (int j = 0; j < 4; ++j) {
            float a = acc[j];
#pragma unroll
            for (int m = 32; m; m >>= 1) a += __shfl_xor(a, m, 64);
            if (lane == 0 && (r0 + j) < 250) c0dec[r0 + j] = a + fc2_b[r0 + j];
        }
    }

    grid_bar(ctr, 48);

    // ---------------- Phase D: decoder, scalar per lane ----------------
    if (blk < 4 && tid < 64) {
        const int b = blk * 64 + tid;
        const bool bv = b < 250;
        const int bs = bv ? b : 0;

        // All four gates in-lane; pre-scaled (i,f,o: -log2e; g: +2log2e).
        float wi[4], wf[4], wg[4], wo[4];
#pragma unroll
        for (int j = 0; j < 4; ++j) {
            wi[j] = dwih[0 * 4 + j] * (-L2E);
            wf[j] = dwih[1 * 4 + j] * (-L2E);
            wg[j] = dwih[2 * 4 + j] * (2.0f * L2E);
            wo[j] = dwih[3 * 4 + j] * (-L2E);
        }
        const float whi = dwhh[0] * (-L2E), whf = dwhh[1] * (-L2E);
        const float whg = dwhh[2] * (2.0f * L2E), who = dwhh[3] * (-L2E);
        const float bi = dbias[0] * (-L2E), bf = dbias[1] * (-L2E);
        const float bg = dbias[2] * (2.0f * L2E), bo = dbias[3] * (-L2E);

        float h = h0_dec[bs];
        float c = c0dec[bs];

        const float4* Y = (const float4*)yws;   // Y[t*250+b] = y[t,b,0:4]
        float4 A0 = Y[0 * 250 + bs], A1 = Y[1 * 250 + bs];
        float4 A2 = Y[2 * 250 + bs], A3 = Y[3 * 250 + bs];
        float4 B0 = Y[4 * 250 + bs], B1 = Y[5 * 250 + bs];
        float4 B2 = Y[6 * 250 + bs], B3 = Y[7 * 250 + bs];

        float* op = bv ? (out + b) : (dump + 1024 + blk * 64 + tid);
        const int oinc = bv ? 250 : 0;

#define DEC_STEP(YV) do {                                                     \
    const float basei = fmaf((YV).w, wi[3], fmaf((YV).z, wi[2],               \
                        fmaf((YV).y, wi[1], fmaf((YV).x, wi[0], bi))));       \
    const float basef = fmaf((YV).w, wf[3], fmaf((YV).z, wf[2],               \
                        fmaf((YV).y, wf[1], fmaf((YV).x, wf[0], bf))));       \
    const float baseg = fmaf((YV).w, wg[3], fmaf((YV).z, wg[2],               \
                        fmaf((YV).y, wg[1], fmaf((YV).x, wg[0], bg))));       \
    const float baseo = fmaf((YV).w, wo[3], fmaf((YV).z, wo[2],               \
                        fmaf((YV).y, wo[1], fmaf((YV).x, wo[0], bo))));       \
    const float ri = rcp_fast(1.0f + exp2_fast(fmaf(h, whi, basei)));         \
    const float rf = rcp_fast(1.0f + exp2_fast(fmaf(h, whf, basef)));         \
    const float rg = rcp_fast(1.0f + exp2_fast(fmaf(h, whg, baseg)));         \
    const float ro = rcp_fast(1.0f + exp2_fast(fmaf(h, who, baseo)));         \
    const float tg = fmaf(-2.0f, rg, 1.0f);                                   \
    c = fmaf(rf, c, ri * tg);                                                 \
    const float n2ro = -2.0f * ro;                                            \
    const float r2 = rcp_fast(1.0f + exp2_fast(c * K2));                      \
    h = fmaf(n2ro, r2, ro);                                                   \
    *op = h; op += oinc;                                                      \
} while (0)

        for (int tb = 0; tb < 62; ++tb) {
            const int nb = (tb + 2) * 4;
            const float4 C0 = Y[min(nb + 0, 249) * 250 + bs];
            const float4 C1 = Y[min(nb + 1, 249) * 250 + bs];
            const float4 C2 = Y[min(nb + 2, 249) * 250 + bs];
            const float4 C3 = Y[min(nb + 3, 249) * 250 + bs];
            DEC_STEP(A0); DEC_STEP(A1); DEC_STEP(A2); DEC_STEP(A3);
            A0 = B0; A1 = B1; A2 = B2; A3 = B3;
            B0 = C0; B1 = C1; B2 = C2; B3 = C3;
        }
        DEC_STEP(A0); DEC_STEP(A1);   // steps 248, 249
#undef DEC_STEP
    }
}

extern "C" void kernel_launch(void* const* d_in, const int* in_sizes, int n_in,
                              void* d_out, int out_size, void* d_ws, size_t ws_size,
                              hipStream_t stream) {
    const float* x        = (const float*)d_in[0];
    const float* h0_dec   = (const float*)d_in[1];
    const float* enc_w_ih = (const float*)d_in[2];
    const float* enc_w_hh = (const float*)d_in[3];
    const float* enc_b    = (const float*)d_in[4];
    const float* fc1_w    = (const float*)d_in[5];
    const float* fc1_b    = (const float*)d_in[6];
    const float* fc2_w    = (const float*)d_in[7];
    const float* fc2_b    = (const float*)d_in[8];
    const float* dec_w_ih = (const float*)d_in[9];
    const float* dec_w_hh = (const float*)d_in[10];
    const float* dec_b    = (const float*)d_in[11];
    float* out = (float*)d_out;

    float* ws    = (float*)d_ws;
    float* yws   = ws;               // 250*250*4 = 250000 floats
    float* cfin  = ws + 250000;      // 1000
    float* out1  = ws + 251008;      // 512
    float* c0dec = ws + 251520;      // 256
    float* dump  = ws + 251776;      // 2048 (enc + dec dead stores)
    int*   ctr   = (int*)(ws + 253824);

    hipMemsetAsync(ctr, 0, sizeof(int), stream);
    fused_kernel<<<dim3(16), dim3(256), 0, stream>>>(
        x, h0_dec, enc_w_ih, enc_w_hh, enc_b, fc1_w, fc1_b, fc2_w, fc2_b,
        dec_w_ih, dec_w_hh, dec_b, out, yws, cfin, out1, c0dec, dump, ctr);
}